// Round 5
// baseline (406.776 us; speedup 1.0000x reference)
//
#include <hip/hip_runtime.h>
#include <hip/hip_fp8.h>

#define EMB 1024
#define HID 4096
#define NB 2
#define TT 4096
#define MROWS (NB*TT)   // 8192
#define N1 (2*HID)      // 8192
#define CHUNK 128       // = GEMM1 row tile
#define NCH 32          // chunks per batch (TT/CHUNK)

typedef short short8 __attribute__((ext_vector_type(8)));
typedef float v4f   __attribute__((ext_vector_type(4)));
typedef int   v4i   __attribute__((ext_vector_type(4)));
typedef int   v8i   __attribute__((ext_vector_type(8)));

__device__ __forceinline__ unsigned short f2bf(float f) {
  unsigned int u = __float_as_uint(f);
  u += 0x7FFFu + ((u >> 16) & 1u);
  return (unsigned short)(u >> 16);
}
__device__ __forceinline__ float bf2f(unsigned short s) {
  return __uint_as_float(((unsigned int)s) << 16);
}
__device__ __forceinline__ unsigned char f2e4m3(float f) {
  __hip_fp8_e4m3 q(f);
  return *(unsigned char*)&q;
}
__device__ __forceinline__ float e4m32f(unsigned char c) {
  __hip_fp8_e4m3 q = *(__hip_fp8_e4m3*)&c;
  return (float)q;
}
__device__ __forceinline__ void g2l16(const void* g, void* l) {
  __builtin_amdgcn_global_load_lds(
      (const __attribute__((address_space(1))) void*)g,
      (__attribute__((address_space(3))) void*)l, 16, 0, 0);
}

__device__ __forceinline__ float block_reduce_sum(float v, float* sbuf) {
  #pragma unroll
  for (int off = 32; off; off >>= 1) v += __shfl_down(v, off, 64);
  int lane = threadIdx.x & 63, w = threadIdx.x >> 6;
  if (lane == 0) sbuf[w] = v;
  __syncthreads();
  return sbuf[0] + sbuf[1] + sbuf[2] + sbuf[3];
}

// ---------- merged weight convert: W1|W2 -> bf16, W3 -> fp8 x64 ----------
__global__ __launch_bounds__(256) void conv_all(const float* __restrict__ W1,
                                                const float* __restrict__ W2,
                                                const float* __restrict__ W3,
                                                unsigned short* __restrict__ o12,
                                                unsigned char* __restrict__ o3) {
  size_t i = ((size_t)blockIdx.x*256 + threadIdx.x)*4;
  if (i < 2ull*HID*EMB) {
    const float* s = (i < (size_t)HID*EMB) ? (W1 + i) : (W2 + (i - (size_t)HID*EMB));
    float4 v = *(const float4*)s;
    ushort4 u; u.x=f2bf(v.x); u.y=f2bf(v.y); u.z=f2bf(v.z); u.w=f2bf(v.w);
    *(ushort4*)(o12 + i) = u;
  } else {
    size_t off = i - 2ull*HID*EMB;
    float4 v = *(const float4*)(W3 + off);
    uchar4 u; u.x=f2e4m3(v.x*64.f); u.y=f2e4m3(v.y*64.f);
             u.z=f2e4m3(v.z*64.f); u.w=f2e4m3(v.w*64.f);
    *(uchar4*)(o3 + off) = u;
  }
}

// ---------- rmsnorm (fp32 in, bf16 out), row = EMB ----------
__global__ __launch_bounds__(256) void rmsnorm_x(const float* __restrict__ x,
                                                 unsigned short* __restrict__ r) {
  __shared__ float sbuf[4];
  int row = blockIdx.x;
  float4 v = *(const float4*)(x + (size_t)row*EMB + threadIdx.x*4);
  float ss = v.x*v.x + v.y*v.y + v.z*v.z + v.w*v.w;
  float tot = block_reduce_sum(ss, sbuf);
  float sc = rsqrtf(tot * (1.0f/EMB) + 1e-6f);
  ushort4 o; o.x=f2bf(v.x*sc); o.y=f2bf(v.y*sc); o.z=f2bf(v.z*sc); o.w=f2bf(v.w*sc);
  *(ushort4*)(r + (size_t)row*EMB + threadIdx.x*4) = o;
}

// ---------- GEMM1: C8 = (fp8 e4m3) exp(A*Bt^T); col-chunk sums -> part ----------
// bf16 MFMA, 128x128 tile, BK=64, XOR-swizzled LDS (32 KB).
// XCD-aware swizzle: 1D grid 4096; xcd = bid&7 owns col-stripe [xcd*8, xcd*8+8);
// within stripe, cols cycle fastest so the A row-tile is reused 8x while L2-hot.
// NOTE (R1/R2 post-mortem): 256^2 8-phase/counted-vmcnt restructures measured
// SLOWER here (161-167us vs 137us): 128KB LDS -> 1 block/CU kills the
// inter-block overlap this 3-blocks/CU structure gets for free (m114).
__global__ __launch_bounds__(256, 2)
void gemm_exp(const unsigned short* __restrict__ A,
              const unsigned short* __restrict__ Bt,
              unsigned char* __restrict__ C8,
              float* __restrict__ part,
              int K, int N) {
  __shared__ short lA[128*64];
  __shared__ short lB[128*64];
  const int tid  = threadIdx.x;
  const int lane = tid & 63;
  const int wm   = (tid >> 6) >> 1, wn = (tid >> 6) & 1;
  const int bid  = blockIdx.x;
  const int s0i  = bid >> 3;
  const int rowTile = s0i >> 3;                       // 0..63
  const int colTile = ((bid & 7) << 3) | (s0i & 7);   // 0..63
  const int rowBase = rowTile * 128;
  const int colBase = colTile * 128;

  v4f acc[4][4];
  #pragma unroll
  for (int i=0;i<4;++i)
    #pragma unroll
    for (int j=0;j<4;++j) acc[i][j] = (v4f){0.f,0.f,0.f,0.f};

  for (int k0 = 0; k0 < K; k0 += 64) {
    #pragma unroll
    for (int j = 0; j < 4; ++j) {
      int s = j*256 + tid;
      int m = s >> 3;
      int c = (s & 7) ^ (m & 7);
      g2l16(A + (size_t)(rowBase + m)*K + k0 + c*8, &lA[s*8]);
    }
    #pragma unroll
    for (int j = 0; j < 4; ++j) {
      int s = j*256 + tid;
      int m = s >> 3;
      int c = (s & 7) ^ (m & 7);
      g2l16(Bt + (size_t)(colBase + m)*K + k0 + c*8, &lB[s*8]);
    }
    __syncthreads();
    #pragma unroll
    for (int s2 = 0; s2 < 2; ++s2) {
      const int quad = lane >> 4;
      const int cc = s2*4 + quad;
      short8 aF[4], bF[4];
      #pragma unroll
      for (int mt = 0; mt < 4; ++mt) {
        int ml = wm*64 + mt*16 + (lane & 15);
        aF[mt] = *(const short8*)&lA[(ml*8 + (cc ^ (ml & 7)))*8];
      }
      #pragma unroll
      for (int nt = 0; nt < 4; ++nt) {
        int nl = wn*64 + nt*16 + (lane & 15);
        bF[nt] = *(const short8*)&lB[(nl*8 + (cc ^ (nl & 7)))*8];
      }
      #pragma unroll
      for (int mt = 0; mt < 4; ++mt)
        #pragma unroll
        for (int nt = 0; nt < 4; ++nt)
          acc[mt][nt] = __builtin_amdgcn_mfma_f32_16x16x32_bf16(aF[mt], bF[nt], acc[mt][nt], 0, 0, 0);
    }
    __syncthreads();
  }

  const int quad = lane >> 4, c15 = lane & 15;
  float csum[4] = {0.f, 0.f, 0.f, 0.f};
  #pragma unroll
  for (int mt = 0; mt < 4; ++mt) {
    #pragma unroll
    for (int nt = 0; nt < 4; ++nt) {
      int col = colBase + wn*64 + nt*16 + c15;
      #pragma unroll
      for (int r = 0; r < 4; ++r) {
        int row = rowBase + wm*64 + mt*16 + quad*4 + r;
        size_t idx = (size_t)row*N + col;
        float e = __expf(acc[mt][nt][r]);
        C8[idx] = f2e4m3(e);
        csum[nt] += e;
      }
    }
  }
  float* cs = (float*)lA;   // [2][128], reuses dead lA
  #pragma unroll
  for (int nt = 0; nt < 4; ++nt) {
    float s = csum[nt];
    s += __shfl_xor(s, 16, 64);
    s += __shfl_xor(s, 32, 64);
    if (lane < 16) cs[wm*128 + wn*64 + nt*16 + lane] = s;
  }
  __syncthreads();
  if (tid < 128)
    part[(size_t)(colBase + tid)*64 + rowTile] = cs[tid] + cs[128 + tid];
}

// ---------- GEMM2 (fp8, MX-unit-scale): out = x + sc_row*(1/16)*y8*(w3*64)^T
// 128x128 tile, BK=128 fp8. mfma_scale_f32_16x16x128_f8f6f4 with E8M0 unit
// scales (0x7F): bit-identical math to plain fp8 MFMA at the MX rate.
// Per-row rmsnorm scale applied in the EPILOGUE (a row scale commutes with
// the h-contraction), so normq/y_bf round-trips are eliminated:
//   y8 = fp8(y*0.25), acc = 16*(y@W3t), out = x + rsqrt(mean y^2+eps)*acc/16.
// Grid (row=64, col=8) = 512 blocks = 2/CU; B-panel (4 MB) is L2-resident.
__global__ __launch_bounds__(256, 2)
void gemm_out(const unsigned char* __restrict__ A8,
              const unsigned char* __restrict__ B8,
              const float* __restrict__ x,
              const float* __restrict__ rsq,
              float* __restrict__ out,
              int K, int N) {
  __shared__ unsigned char lA8[128*128];
  __shared__ unsigned char lB8[128*128];
  const int tid  = threadIdx.x;
  const int lane = tid & 63;
  const int wm   = (tid >> 6) >> 1, wn = (tid >> 6) & 1;
  const int rowBase = blockIdx.x * 128;
  const int colBase = blockIdx.y * 128;
  const int q   = lane >> 4;     // k-block 0..3 (32 fp8 each)
  const int r15 = lane & 15;

  v4f acc[4][4];
  #pragma unroll
  for (int i=0;i<4;++i)
    #pragma unroll
    for (int j=0;j<4;++j) acc[i][j] = (v4f){0.f,0.f,0.f,0.f};

  for (int k0 = 0; k0 < K; k0 += 128) {
    #pragma unroll
    for (int j = 0; j < 4; ++j) {
      int s = j*256 + tid;
      int m = s >> 3;
      int c = (s & 7) ^ (m & 7);
      g2l16(A8 + (size_t)(rowBase + m)*K + k0 + c*16, &lA8[s*16]);
    }
    #pragma unroll
    for (int j = 0; j < 4; ++j) {
      int s = j*256 + tid;
      int m = s >> 3;
      int c = (s & 7) ^ (m & 7);
      g2l16(B8 + (size_t)(colBase + m)*K + k0 + c*16, &lB8[s*16]);
    }
    __syncthreads();
    v8i aF[4], bF[4];
    #pragma unroll
    for (int mt = 0; mt < 4; ++mt) {
      int ml = wm*64 + mt*16 + r15;
      int s  = ml & 7;
      v4i lo = *(const v4i*)&lA8[ml*128 + (((2*q)   ^ s)<<4)];
      v4i hi = *(const v4i*)&lA8[ml*128 + (((2*q+1) ^ s)<<4)];
      aF[mt] = __builtin_shufflevector(lo, hi, 0,1,2,3,4,5,6,7);
    }
    #pragma unroll
    for (int nt = 0; nt < 4; ++nt) {
      int nl = wn*64 + nt*16 + r15;
      int s  = nl & 7;
      v4i lo = *(const v4i*)&lB8[nl*128 + (((2*q)   ^ s)<<4)];
      v4i hi = *(const v4i*)&lB8[nl*128 + (((2*q+1) ^ s)<<4)];
      bF[nt] = __builtin_shufflevector(lo, hi, 0,1,2,3,4,5,6,7);
    }
    #pragma unroll
    for (int mt = 0; mt < 4; ++mt)
      #pragma unroll
      for (int nt = 0; nt < 4; ++nt)
        acc[mt][nt] = __builtin_amdgcn_mfma_scale_f32_16x16x128_f8f6f4(
            aF[mt], bF[nt], acc[mt][nt],
            0, 0,                      // cbsz=fp8(e4m3), blgp=fp8(e4m3)
            0, 0x7F7F7F7F,             // opsel_a, scale_a = E8M0 1.0
            0, 0x7F7F7F7F);            // opsel_b, scale_b = E8M0 1.0
    __syncthreads();
  }

  const int quad = lane >> 4, c15 = lane & 15;
  #pragma unroll
  for (int mt = 0; mt < 4; ++mt) {
    #pragma unroll
    for (int nt = 0; nt < 4; ++nt) {
      int col = colBase + wn*64 + nt*16 + c15;
      #pragma unroll
      for (int r = 0; r < 4; ++r) {
        int row = rowBase + wm*64 + mt*16 + quad*4 + r;
        size_t idx = (size_t)row*N + col;
        float sc = rsqrtf(rsq[row]*(1.0f/HID) + 1e-6f) * 0.0625f;
        out[idx] = x[idx] + sc*acc[mt][nt][r];
      }
    }
  }
}

// ---------- exclusive prefix over 32 chunks per (col, batch); zero rsq ------
__global__ __launch_bounds__(256) void scan_prefix(float* __restrict__ part,
                                                   float* __restrict__ rsq) {
  int idx = blockIdx.x*256 + threadIdx.x;   // 0..16383
  if (idx < MROWS) rsq[idx] = 0.f;          // re-zeroed every graph replay
  int col = idx >> 1, bb = idx & 1;
  float* p = part + (size_t)col*64 + bb*NCH;
  float run = 0.f;
  #pragma unroll
  for (int c = 0; c < NCH; ++c) { float v = p[c]; p[c] = run; run += v; }
}

// ---------- emit y8 = fp8(0.25*Sa*Sb/t^2); rowsum(y^2) -> rsq (atomics) -----
// Per-row rmsnorm scale is deferred to gemm_out's epilogue (it commutes with
// the h-contraction), killing the old y_bf(64MB) round-trip + normq kernel.
__global__ __launch_bounds__(256) void scan_emit(const unsigned char* __restrict__ ab,
                                                 const float* __restrict__ part,
                                                 unsigned char* __restrict__ y8,
                                                 float* __restrict__ rsq) {
  int h = blockIdx.x*256 + threadIdx.x;     // 0..4095
  int cy = blockIdx.y, bb = blockIdx.z;
  int lane = threadIdx.x & 63;
  float sa = part[(size_t)h*64 + bb*NCH + cy];
  float sb = part[(size_t)(HID + h)*64 + bb*NCH + cy];
  const unsigned char* pa = ab + ((size_t)(bb*TT + cy*CHUNK))*N1 + h;
  const unsigned char* pb = pa + HID;
  unsigned char* py = y8 + ((size_t)(bb*TT + cy*CHUNK))*HID + h;
  float* prs = rsq + bb*TT + cy*CHUNK;
  int t0 = cy*CHUNK;
  #pragma unroll 4
  for (int i = 0; i < CHUNK; ++i) {
    sa += e4m32f(pa[(size_t)i*N1]);
    sb += e4m32f(pb[(size_t)i*N1]);
    float inv = __builtin_amdgcn_rcpf((float)(t0 + i + 1));
    float y = sa*sb*inv*inv;
    py[(size_t)i*HID] = f2e4m3(y*0.25f);
    float s2 = y*y;
    #pragma unroll
    for (int off = 32; off; off >>= 1) s2 += __shfl_xor(s2, off, 64);
    if (lane == 0) atomicAdd(&prs[i], s2);
  }
}

extern "C" void kernel_launch(void* const* d_in, const int* in_sizes, int n_in,
                              void* d_out, int out_size, void* d_ws, size_t ws_size,
                              hipStream_t stream) {
  const float* x  = (const float*)d_in[0];
  const float* W1 = (const float*)d_in[1];
  const float* W2 = (const float*)d_in[2];
  const float* W3 = (const float*)d_in[3];
  float* out = (float*)d_out;
  char* ws = (char*)d_ws;

  unsigned short* r_bf   = (unsigned short*)(ws);                 // 16 MiB
  unsigned short* w12_bf = (unsigned short*)(ws + 16777216ull);   // 16 MiB
  unsigned char*  w3_8   = (unsigned char*) (ws + 33554432ull);   // 4 MiB fp8 (x64)
  unsigned char*  ab8    = (unsigned char*) (ws + 37748736ull);   // 64 MiB fp8
  float*          rsq    = (float*)        (ws + 104857600ull);   // 32 KiB rowsum(y^2)
  unsigned char*  y8     = (unsigned char*) (ws + 171966464ull);  // 32 MiB fp8 (0.25*y)
  // part (per-chunk column sums) lives in d_out; dead before gemm_out
  float*          part   = (float*)d_out;                         // 2 MB

  conv_all<<<12288, 256, 0, stream>>>(W1, W2, W3, w12_bf, w3_8);
  rmsnorm_x<<<MROWS, 256, 0, stream>>>(x, r_bf);
  gemm_exp<<<4096, 256, 0, stream>>>(r_bf, w12_bf, ab8, part, EMB, N1);
  scan_prefix<<<64, 256, 0, stream>>>(part, rsq);
  scan_emit<<<dim3(16,NCH,2), 256, 0, stream>>>(ab8, part, y8, rsq);
  gemm_out<<<dim3(64,8), 256, 0, stream>>>(y8, w3_8, x, rsq, out, HID, EMB);
}

// Round 6
// 335.771 us; speedup vs baseline: 1.2115x; 1.2115x over previous
//
#include <hip/hip_runtime.h>
#include <hip/hip_fp8.h>

#define EMB 1024
#define HID 4096
#define NB 2
#define TT 4096
#define MROWS (NB*TT)   // 8192
#define N1 (2*HID)      // 8192
#define CHUNK 128       // = GEMM1 row tile
#define NCH 32          // chunks per batch (TT/CHUNK)

typedef short short8 __attribute__((ext_vector_type(8)));
typedef float v4f   __attribute__((ext_vector_type(4)));
typedef int   v4i   __attribute__((ext_vector_type(4)));
typedef int   v8i   __attribute__((ext_vector_type(8)));

__device__ __forceinline__ unsigned short f2bf(float f) {
  unsigned int u = __float_as_uint(f);
  u += 0x7FFFu + ((u >> 16) & 1u);
  return (unsigned short)(u >> 16);
}
__device__ __forceinline__ float bf2f(unsigned short s) {
  return __uint_as_float(((unsigned int)s) << 16);
}
__device__ __forceinline__ unsigned char f2e4m3(float f) {
  __hip_fp8_e4m3 q(f);
  return *(unsigned char*)&q;
}
__device__ __forceinline__ float e4m32f(unsigned char c) {
  __hip_fp8_e4m3 q = *(__hip_fp8_e4m3*)&c;
  return (float)q;
}
__device__ __forceinline__ void g2l16(const void* g, void* l) {
  __builtin_amdgcn_global_load_lds(
      (const __attribute__((address_space(1))) void*)g,
      (__attribute__((address_space(3))) void*)l, 16, 0, 0);
}

__device__ __forceinline__ float block_reduce_sum(float v, float* sbuf) {
  #pragma unroll
  for (int off = 32; off; off >>= 1) v += __shfl_down(v, off, 64);
  int lane = threadIdx.x & 63, w = threadIdx.x >> 6;
  if (lane == 0) sbuf[w] = v;
  __syncthreads();
  return sbuf[0] + sbuf[1] + sbuf[2] + sbuf[3];
}

// ---------- merged weight convert: W1|W2 -> bf16, W3 -> fp8 x64 ----------
__global__ __launch_bounds__(256) void conv_all(const float* __restrict__ W1,
                                                const float* __restrict__ W2,
                                                const float* __restrict__ W3,
                                                unsigned short* __restrict__ o12,
                                                unsigned char* __restrict__ o3) {
  size_t i = ((size_t)blockIdx.x*256 + threadIdx.x)*4;
  if (i < 2ull*HID*EMB) {
    const float* s = (i < (size_t)HID*EMB) ? (W1 + i) : (W2 + (i - (size_t)HID*EMB));
    float4 v = *(const float4*)s;
    ushort4 u; u.x=f2bf(v.x); u.y=f2bf(v.y); u.z=f2bf(v.z); u.w=f2bf(v.w);
    *(ushort4*)(o12 + i) = u;
  } else {
    size_t off = i - 2ull*HID*EMB;
    float4 v = *(const float4*)(W3 + off);
    uchar4 u; u.x=f2e4m3(v.x*64.f); u.y=f2e4m3(v.y*64.f);
             u.z=f2e4m3(v.z*64.f); u.w=f2e4m3(v.w*64.f);
    *(uchar4*)(o3 + off) = u;
  }
}

// ---------- rmsnorm (fp32 in, bf16 out), row = EMB ----------
__global__ __launch_bounds__(256) void rmsnorm_x(const float* __restrict__ x,
                                                 unsigned short* __restrict__ r) {
  __shared__ float sbuf[4];
  int row = blockIdx.x;
  float4 v = *(const float4*)(x + (size_t)row*EMB + threadIdx.x*4);
  float ss = v.x*v.x + v.y*v.y + v.z*v.z + v.w*v.w;
  float tot = block_reduce_sum(ss, sbuf);
  float sc = rsqrtf(tot * (1.0f/EMB) + 1e-6f);
  ushort4 o; o.x=f2bf(v.x*sc); o.y=f2bf(v.y*sc); o.z=f2bf(v.z*sc); o.w=f2bf(v.w*sc);
  *(ushort4*)(r + (size_t)row*EMB + threadIdx.x*4) = o;
}

// ---------- GEMM1: C8 = (fp8 e4m3) exp(A*Bt^T); col-chunk sums -> part ----------
// bf16 MFMA, 128x128 tile, BK=64, XOR-swizzled LDS (32 KB).
// XCD-aware swizzle: 1D grid 4096; xcd = bid&7 owns col-stripe [xcd*8, xcd*8+8);
// within stripe, cols cycle fastest so the A row-tile is reused 8x while L2-hot.
// NOTE (R1/R2 post-mortem): 256^2 8-phase/counted-vmcnt restructures measured
// SLOWER here (161-167us vs 137us): 128KB LDS -> 1 block/CU kills the
// inter-block overlap this 3-blocks/CU structure gets for free (m114).
__global__ __launch_bounds__(256, 2)
void gemm_exp(const unsigned short* __restrict__ A,
              const unsigned short* __restrict__ Bt,
              unsigned char* __restrict__ C8,
              float* __restrict__ part,
              int K, int N) {
  __shared__ short lA[128*64];
  __shared__ short lB[128*64];
  const int tid  = threadIdx.x;
  const int lane = tid & 63;
  const int wm   = (tid >> 6) >> 1, wn = (tid >> 6) & 1;
  const int bid  = blockIdx.x;
  const int s0i  = bid >> 3;
  const int rowTile = s0i >> 3;                       // 0..63
  const int colTile = ((bid & 7) << 3) | (s0i & 7);   // 0..63
  const int rowBase = rowTile * 128;
  const int colBase = colTile * 128;

  v4f acc[4][4];
  #pragma unroll
  for (int i=0;i<4;++i)
    #pragma unroll
    for (int j=0;j<4;++j) acc[i][j] = (v4f){0.f,0.f,0.f,0.f};

  for (int k0 = 0; k0 < K; k0 += 64) {
    #pragma unroll
    for (int j = 0; j < 4; ++j) {
      int s = j*256 + tid;
      int m = s >> 3;
      int c = (s & 7) ^ (m & 7);
      g2l16(A + (size_t)(rowBase + m)*K + k0 + c*8, &lA[s*8]);
    }
    #pragma unroll
    for (int j = 0; j < 4; ++j) {
      int s = j*256 + tid;
      int m = s >> 3;
      int c = (s & 7) ^ (m & 7);
      g2l16(Bt + (size_t)(colBase + m)*K + k0 + c*8, &lB[s*8]);
    }
    __syncthreads();
    #pragma unroll
    for (int s2 = 0; s2 < 2; ++s2) {
      const int quad = lane >> 4;
      const int cc = s2*4 + quad;
      short8 aF[4], bF[4];
      #pragma unroll
      for (int mt = 0; mt < 4; ++mt) {
        int ml = wm*64 + mt*16 + (lane & 15);
        aF[mt] = *(const short8*)&lA[(ml*8 + (cc ^ (ml & 7)))*8];
      }
      #pragma unroll
      for (int nt = 0; nt < 4; ++nt) {
        int nl = wn*64 + nt*16 + (lane & 15);
        bF[nt] = *(const short8*)&lB[(nl*8 + (cc ^ (nl & 7)))*8];
      }
      #pragma unroll
      for (int mt = 0; mt < 4; ++mt)
        #pragma unroll
        for (int nt = 0; nt < 4; ++nt)
          acc[mt][nt] = __builtin_amdgcn_mfma_f32_16x16x32_bf16(aF[mt], bF[nt], acc[mt][nt], 0, 0, 0);
    }
    __syncthreads();
  }

  const int quad = lane >> 4, c15 = lane & 15;
  float csum[4] = {0.f, 0.f, 0.f, 0.f};
  #pragma unroll
  for (int mt = 0; mt < 4; ++mt) {
    #pragma unroll
    for (int nt = 0; nt < 4; ++nt) {
      int col = colBase + wn*64 + nt*16 + c15;
      #pragma unroll
      for (int r = 0; r < 4; ++r) {
        int row = rowBase + wm*64 + mt*16 + quad*4 + r;
        size_t idx = (size_t)row*N + col;
        float e = __expf(acc[mt][nt][r]);
        C8[idx] = f2e4m3(e);
        csum[nt] += e;
      }
    }
  }
  float* cs = (float*)lA;   // [2][128], reuses dead lA
  #pragma unroll
  for (int nt = 0; nt < 4; ++nt) {
    float s = csum[nt];
    s += __shfl_xor(s, 16, 64);
    s += __shfl_xor(s, 32, 64);
    if (lane < 16) cs[wm*128 + wn*64 + nt*16 + lane] = s;
  }
  __syncthreads();
  if (tid < 128)
    part[(size_t)(colBase + tid)*64 + rowTile] = cs[tid] + cs[128 + tid];
}

// ---------- GEMM2 (fp8, MX-unit-scale): out = x + sc_row*(1/16)*y8*(w3*64)^T
// 128x128 tile, BK=128 fp8. mfma_scale_f32_16x16x128_f8f6f4 with E8M0 unit
// scales (0x7F): bit-identical math to plain fp8 MFMA at the MX rate.
// Per-row rmsnorm scale applied in the EPILOGUE (a row scale commutes with
// the h-contraction): y8 = fp8(0.25*y), rsq = sum((0.25*y)^2) from rowss,
// mean(y^2) = 16*rsq/HID, out = x + rsqrt(mean+eps)*acc/16.
// Grid (row=64, col=8) = 512 blocks = 2/CU; B-panel (4 MB) is L2-resident.
__global__ __launch_bounds__(256, 2)
void gemm_out(const unsigned char* __restrict__ A8,
              const unsigned char* __restrict__ B8,
              const float* __restrict__ x,
              const float* __restrict__ rsq,
              float* __restrict__ out,
              int K, int N) {
  __shared__ unsigned char lA8[128*128];
  __shared__ unsigned char lB8[128*128];
  const int tid  = threadIdx.x;
  const int lane = tid & 63;
  const int wm   = (tid >> 6) >> 1, wn = (tid >> 6) & 1;
  const int rowBase = blockIdx.x * 128;
  const int colBase = blockIdx.y * 128;
  const int q   = lane >> 4;     // k-block 0..3 (32 fp8 each)
  const int r15 = lane & 15;

  v4f acc[4][4];
  #pragma unroll
  for (int i=0;i<4;++i)
    #pragma unroll
    for (int j=0;j<4;++j) acc[i][j] = (v4f){0.f,0.f,0.f,0.f};

  for (int k0 = 0; k0 < K; k0 += 128) {
    #pragma unroll
    for (int j = 0; j < 4; ++j) {
      int s = j*256 + tid;
      int m = s >> 3;
      int c = (s & 7) ^ (m & 7);
      g2l16(A8 + (size_t)(rowBase + m)*K + k0 + c*16, &lA8[s*16]);
    }
    #pragma unroll
    for (int j = 0; j < 4; ++j) {
      int s = j*256 + tid;
      int m = s >> 3;
      int c = (s & 7) ^ (m & 7);
      g2l16(B8 + (size_t)(colBase + m)*K + k0 + c*16, &lB8[s*16]);
    }
    __syncthreads();
    v8i aF[4], bF[4];
    #pragma unroll
    for (int mt = 0; mt < 4; ++mt) {
      int ml = wm*64 + mt*16 + r15;
      int s  = ml & 7;
      v4i lo = *(const v4i*)&lA8[ml*128 + (((2*q)   ^ s)<<4)];
      v4i hi = *(const v4i*)&lA8[ml*128 + (((2*q+1) ^ s)<<4)];
      aF[mt] = __builtin_shufflevector(lo, hi, 0,1,2,3,4,5,6,7);
    }
    #pragma unroll
    for (int nt = 0; nt < 4; ++nt) {
      int nl = wn*64 + nt*16 + r15;
      int s  = nl & 7;
      v4i lo = *(const v4i*)&lB8[nl*128 + (((2*q)   ^ s)<<4)];
      v4i hi = *(const v4i*)&lB8[nl*128 + (((2*q+1) ^ s)<<4)];
      bF[nt] = __builtin_shufflevector(lo, hi, 0,1,2,3,4,5,6,7);
    }
    #pragma unroll
    for (int mt = 0; mt < 4; ++mt)
      #pragma unroll
      for (int nt = 0; nt < 4; ++nt)
        acc[mt][nt] = __builtin_amdgcn_mfma_scale_f32_16x16x128_f8f6f4(
            aF[mt], bF[nt], acc[mt][nt],
            0, 0,                      // cbsz=fp8(e4m3), blgp=fp8(e4m3)
            0, 0x7F7F7F7F,             // opsel_a, scale_a = E8M0 1.0
            0, 0x7F7F7F7F);            // opsel_b, scale_b = E8M0 1.0
    __syncthreads();
  }

  const int quad = lane >> 4, c15 = lane & 15;
  #pragma unroll
  for (int mt = 0; mt < 4; ++mt) {
    // hoist per-row scale: rsq = sum((y/4)^2); mean(y^2) = rsq/256
    float scr[4];
    #pragma unroll
    for (int r = 0; r < 4; ++r) {
      int row = rowBase + wm*64 + mt*16 + quad*4 + r;
      scr[r] = rsqrtf(rsq[row]*(1.0f/256.0f) + 1e-6f) * 0.0625f;
    }
    #pragma unroll
    for (int nt = 0; nt < 4; ++nt) {
      int col = colBase + wn*64 + nt*16 + c15;
      #pragma unroll
      for (int r = 0; r < 4; ++r) {
        int row = rowBase + wm*64 + mt*16 + quad*4 + r;
        size_t idx = (size_t)row*N + col;
        out[idx] = x[idx] + scr[r]*acc[mt][nt][r];
      }
    }
  }
}

// ---------- exclusive prefix over 32 chunks per (col, batch) ----------
__global__ __launch_bounds__(256) void scan_prefix(float* __restrict__ part) {
  int idx = blockIdx.x*256 + threadIdx.x;   // 0..16383
  int col = idx >> 1, bb = idx & 1;
  float* p = part + (size_t)col*64 + bb*NCH;
  float run = 0.f;
  #pragma unroll
  for (int c = 0; c < NCH; ++c) { float v = p[c]; p[c] = run; run += v; }
}

// ---------- emit y8 = fp8(0.25*Sa*Sb/t^2), 4 h-channels per thread ----------
// uchar4 loads/stores (256B/wave) instead of the old 1B/lane (64B/wave):
// this kernel was ~35% of total runtime at 0.8 TB/s effective; vectorized
// it is instruction- and latency-efficient. No shuffles, no atomics (the R5
// per-iteration wave-reduce + atomicAdd regressed 354->407; rowsumsq now
// comes from the separate coalesced rowss kernel below).
__global__ __launch_bounds__(256) void scan_emit(const unsigned char* __restrict__ ab,
                                                 const float* __restrict__ part,
                                                 unsigned char* __restrict__ y8) {
  int h0 = (blockIdx.x*256 + threadIdx.x)*4;  // 0..4092, grid.x = 4
  int cy = blockIdx.y, bb = blockIdx.z;
  float sa[4], sb[4];
  #pragma unroll
  for (int j = 0; j < 4; ++j) {
    sa[j] = part[(size_t)(h0+j)*64 + bb*NCH + cy];
    sb[j] = part[(size_t)(HID + h0+j)*64 + bb*NCH + cy];
  }
  const unsigned char* pa = ab + ((size_t)(bb*TT + cy*CHUNK))*N1 + h0;
  const unsigned char* pb = pa + HID;
  unsigned char* py = y8 + ((size_t)(bb*TT + cy*CHUNK))*HID + h0;
  int t0 = cy*CHUNK;
  #pragma unroll 8
  for (int i = 0; i < CHUNK; ++i) {
    uchar4 va = *(const uchar4*)(pa + (size_t)i*N1);
    uchar4 vb = *(const uchar4*)(pb + (size_t)i*N1);
    sa[0] += e4m32f(va.x); sa[1] += e4m32f(va.y);
    sa[2] += e4m32f(va.z); sa[3] += e4m32f(va.w);
    sb[0] += e4m32f(vb.x); sb[1] += e4m32f(vb.y);
    sb[2] += e4m32f(vb.z); sb[3] += e4m32f(vb.w);
    float inv = __builtin_amdgcn_rcpf((float)(t0 + i + 1));
    float i2 = inv*inv*0.25f;
    uchar4 o;
    o.x = f2e4m3(sa[0]*sb[0]*i2); o.y = f2e4m3(sa[1]*sb[1]*i2);
    o.z = f2e4m3(sa[2]*sb[2]*i2); o.w = f2e4m3(sa[3]*sb[3]*i2);
    *(uchar4*)(py + (size_t)i*HID) = o;
  }
}

// ---------- rowss: rsq[row] = sum over h of (y8-decoded)^2 ----------
// Coalesced uint4 (16 fp8/thread); one block per row; no atomics.
__global__ __launch_bounds__(256) void rowss(const unsigned char* __restrict__ y8,
                                             float* __restrict__ rsq) {
  __shared__ float sbuf[4];
  int row = blockIdx.x;
  const unsigned char* p = y8 + (size_t)row*HID + threadIdx.x*16;
  uint4 v = *(const uint4*)p;
  float ss = 0.f;
  unsigned int w[4] = {v.x, v.y, v.z, v.w};
  #pragma unroll
  for (int g = 0; g < 4; ++g)
    #pragma unroll
    for (int b = 0; b < 4; ++b) {
      float f = e4m32f((unsigned char)(w[g] >> (8*b)));
      ss += f*f;
    }
  float tot = block_reduce_sum(ss, sbuf);
  if (threadIdx.x == 0) rsq[row] = tot;
}

extern "C" void kernel_launch(void* const* d_in, const int* in_sizes, int n_in,
                              void* d_out, int out_size, void* d_ws, size_t ws_size,
                              hipStream_t stream) {
  const float* x  = (const float*)d_in[0];
  const float* W1 = (const float*)d_in[1];
  const float* W2 = (const float*)d_in[2];
  const float* W3 = (const float*)d_in[3];
  float* out = (float*)d_out;
  char* ws = (char*)d_ws;

  unsigned short* r_bf   = (unsigned short*)(ws);                 // 16 MiB
  unsigned short* w12_bf = (unsigned short*)(ws + 16777216ull);   // 16 MiB
  unsigned char*  w3_8   = (unsigned char*) (ws + 33554432ull);   // 4 MiB fp8 (x64)
  unsigned char*  ab8    = (unsigned char*) (ws + 37748736ull);   // 64 MiB fp8
  float*          rsq    = (float*)        (ws + 104857600ull);   // 32 KiB rowsum((y/4)^2)
  unsigned char*  y8     = (unsigned char*) (ws + 171966464ull);  // 32 MiB fp8 (0.25*y)
  // part (per-chunk column sums) lives in d_out; dead before gemm_out
  float*          part   = (float*)d_out;                         // 2 MB

  conv_all<<<12288, 256, 0, stream>>>(W1, W2, W3, w12_bf, w3_8);
  rmsnorm_x<<<MROWS, 256, 0, stream>>>(x, r_bf);
  gemm_exp<<<4096, 256, 0, stream>>>(r_bf, w12_bf, ab8, part, EMB, N1);
  scan_prefix<<<64, 256, 0, stream>>>(part);
  scan_emit<<<dim3(4,NCH,2), 256, 0, stream>>>(ab8, part, y8);
  rowss<<<MROWS, 256, 0, stream>>>(y8, rsq);
  gemm_out<<<dim3(64,8), 256, 0, stream>>>(y8, w3_8, x, rsq, out, HID, EMB);
}